// Round 15
// baseline (932.645 us; speedup 1.0000x reference)
//
#include <hip/hip_runtime.h>
#include <hip/hip_bf16.h>

typedef unsigned short u16;
typedef unsigned char  u8;
typedef unsigned int   u32;
typedef unsigned long long u64;

using short8 = __attribute__((ext_vector_type(8))) short;
using f32x4  = __attribute__((ext_vector_type(4))) float;
using f32x16 = __attribute__((ext_vector_type(16))) float;
using u16x8  = __attribute__((ext_vector_type(8))) unsigned short;
using i32x4  = __attribute__((ext_vector_type(4))) int;
using i32x8  = __attribute__((ext_vector_type(8))) int;

#define AS_GLOBAL __attribute__((address_space(1)))
#define AS_LDS    __attribute__((address_space(3)))

// ---- bf16 helpers (manual RNE) ----
__device__ __forceinline__ u16 f2b(float x){
  u32 u = __float_as_uint(x);
  u32 r = (u + 0x7FFFu + ((u >> 16) & 1u)) >> 16;
  return (u16)r;
}
__device__ __forceinline__ float b2f(u16 h){ return __uint_as_float(((u32)h) << 16); }

// ---- fp8 OCP e4m3 (RNE, saturate 448) ----
__device__ __forceinline__ u32 f2e4m3(float x){
  float ax = fabsf(x);
  u32 s = (__float_as_uint(x) & 0x80000000u) >> 24;
  ax = fminf(ax, 448.0f);
  if (ax < 0.015625f){
    u32 m = (u32)__float2int_rn(ax * 512.0f);
    return s | m;
  }
  u32 u = __float_as_uint(ax);
  u32 man = u & 0x7FFFFFu;
  u32 rnd = man + 0x7FFFFu + ((man >> 20) & 1u);
  u32 e = (u >> 23) + (rnd >> 23);
  u32 m = (rnd >> 23) ? 0u : ((rnd >> 20) & 7u);
  if (e > 135u) return s | 0x7Eu;
  return s | ((e - 120u) << 3) | m;
}

__device__ __forceinline__ void gload16(u16* l, const u16* g){
  __builtin_amdgcn_global_load_lds((const AS_GLOBAL u32*)g, (AS_LDS u32*)l, 16, 0, 0);
}

__device__ __forceinline__ u64 umin64(u64 a, u64 b){ return a < b ? a : b; }

__device__ __forceinline__ u64 shfl_xor_u64(u64 v, int m){
  u32 lo = __shfl_xor((u32)v, m, 64);
  u32 hi = __shfl_xor((u32)(v >> 32), m, 64);
  return ((u64)hi << 32) | lo;
}

__device__ __forceinline__ i32x8 cat8(i32x4 lo, i32x4 hi){
  i32x8 r;
  r[0] = lo[0]; r[1] = lo[1]; r[2] = lo[2]; r[3] = lo[3];
  r[4] = hi[0]; r[5] = hi[1]; r[6] = hi[2]; r[7] = hi[3];
  return r;
}

// ---- fused prep mega-kernel (r14 structure; cvt8 now PLAIN k layout) ----
// grid = 21504 x 256thr:
//  [0,8192)      x f32 [256b][512r][256c] -> xb bf16 [b][c][r]
//  [8192,9216)   pre_w -> bf16
//  [9216,10240)  post_w -> bf16
//  [10240,18432) emb -> bf16
//  [18432,20480) emb -> fp8 plain-k (scale 2^20)
//  [20480,21504) cnorm*2^26
__global__ void k_prep(const float* __restrict__ x,
                       const float* __restrict__ pre_w,
                       const float* __restrict__ post_w,
                       const float* __restrict__ emb,
                       u16* __restrict__ xb, u16* __restrict__ prew_b,
                       u16* __restrict__ postw_b, u16* __restrict__ emb_b,
                       u8* __restrict__ emb8, float* __restrict__ cn26){
  __shared__ float t[64][65];
  const int bid = blockIdx.x;
  const int tid = threadIdx.x;

  if (bid < 8192){
    const int b  = bid >> 5;
    const int rb = (bid >> 2) & 7;
    const int cb = bid & 3;
    const float* s = x + ((size_t)b * 512 + (size_t)rb * 64) * 256 + cb * 64;
    #pragma unroll
    for (int j = 0; j < 4; ++j){
      int fl = j * 256 + tid;
      int r = fl >> 4, c4 = (fl & 15) * 4;
      float4 v = *(const float4*)(s + (size_t)r * 256 + c4);
      t[r][c4 + 0] = v.x; t[r][c4 + 1] = v.y; t[r][c4 + 2] = v.z; t[r][c4 + 3] = v.w;
    }
    __syncthreads();
    u16* o = xb + ((size_t)b * 256 + (size_t)cb * 64) * 512 + rb * 64;
    #pragma unroll
    for (int j = 0; j < 2; ++j){
      int fl = j * 256 + tid;
      int c = fl >> 3, r8 = (fl & 7) * 8;
      u16x8 hv;
      #pragma unroll
      for (int i = 0; i < 8; ++i) hv[i] = f2b(t[r8 + i][c]);
      *(u16x8*)(o + (size_t)c * 512 + r8) = hv;
    }
  } else if (bid < 9216){
    int i = (bid - 8192) * 256 + tid;
    prew_b[i] = f2b(pre_w[i]);
  } else if (bid < 10240){
    int i = (bid - 9216) * 256 + tid;
    postw_b[i] = f2b(post_w[i]);
  } else if (bid < 18432){
    int i = (bid - 10240) * 256 + tid;
    emb_b[i] = f2b(emb[i]);
  } else if (bid < 20480){
    int id = (bid - 18432) * 256 + tid;    // dword id, 524288 total (plain k)
    const float* p = emb + (size_t)id * 4;
    u32 w = f2e4m3(p[0] * 1048576.0f)
          | (f2e4m3(p[1] * 1048576.0f) << 8)
          | (f2e4m3(p[2] * 1048576.0f) << 16)
          | (f2e4m3(p[3] * 1048576.0f) << 24);
    *(u32*)(emb8 + (size_t)id * 4) = w;
  } else {
    int wv = tid >> 6, lane = tid & 63;
    int v = (bid - 20480) * 4 + wv;
    const float* r = emb + (size_t)v * 512;
    float s = 0.f;
    #pragma unroll
    for (int i = 0; i < 8; ++i){ float xx = r[lane + i * 64]; s += xx * xx; }
    #pragma unroll
    for (int off = 32; off; off >>= 1) s += __shfl_down(s, off, 64);
    if (lane == 0) cn26[v] = s * 67108864.0f;
  }
}

// ---- small GEMM (proven 128x128 2-phase): GEMM1 ----
// MODE 0 writes C=z (f32) + z8 = fp8(z*64) PLAIN-k transposed from registers.
template<int MODE>
__global__ __launch_bounds__(256, 4) void k_gemm(
    const u16* __restrict__ Ah,
    const u16* __restrict__ Bh,
    const u64* __restrict__ gkeys,
    const float* __restrict__ bias,
    float* __restrict__ Cout,
    u8* __restrict__ Z8,
    int M, int mtbits)
{
  constexpr int K = 512;
  __shared__ __align__(16) u16 sA[128 * 64];
  __shared__ __align__(16) u16 sB[128 * 64];

  const int tid  = threadIdx.x;
  const int lane = tid & 63;
  const int wid  = tid >> 6;
  const int wm = wid >> 1, wn = wid & 1;

  const int nwg = gridDim.x;
  const int chunk = nwg >> 3;
  const int pb = blockIdx.x;
  const int bid = (pb & 7) * chunk + (pb >> 3);

  const int mt = bid & ((1 << mtbits) - 1);
  const int nt = (bid >> mtbits) & 1;
  const int b  = bid >> (mtbits + 1);
  const int m0 = mt * 128;
  const int n0 = nt * 128;
  const int bbase = b * 256;

  const u16* ga[4];
  const u16* gb[4];
  int ldso[4];
  #pragma unroll
  for (int i = 0; i < 4; ++i){
    int e = i * 256 + tid;
    int r = e >> 3;
    int sl = (e & 7) ^ (r & 7);
    ldso[i] = e * 8;
    ga[i] = Ah + (size_t)(m0 + r) * K + sl * 8;
    size_t brow;
    if (MODE == 2) brow = (size_t)(u32)gkeys[bbase + n0 + r];
    else           brow = (size_t)(bbase + n0 + r);
    gb[i] = Bh + brow * K + sl * 8;
  }

  const f32x4 zero4 = {0.f, 0.f, 0.f, 0.f};
  f32x4 acc[4][4];
  #pragma unroll
  for (int i = 0; i < 4; ++i)
    #pragma unroll
    for (int j = 0; j < 4; ++j) acc[i][j] = zero4;

  int aoff[2][4], boff[2][4];
  #pragma unroll
  for (int ks = 0; ks < 2; ++ks)
    #pragma unroll
    for (int f = 0; f < 4; ++f){
      int rA = wm * 64 + f * 16 + (lane & 15);
      aoff[ks][f] = rA * 64 + (((ks * 4 + (lane >> 4)) ^ (rA & 7)) * 8);
      int rB = wn * 64 + f * 16 + (lane & 15);
      boff[ks][f] = rB * 64 + (((ks * 4 + (lane >> 4)) ^ (rB & 7)) * 8);
    }

  for (int kt = 0; kt < 8; ++kt){
    const int k0 = kt * 64;
    #pragma unroll
    for (int i = 0; i < 4; ++i){
      gload16(&sA[ldso[i]], ga[i] + k0);
      gload16(&sB[ldso[i]], gb[i] + k0);
    }
    __syncthreads();
    #pragma unroll
    for (int ks = 0; ks < 2; ++ks){
      short8 ah[4], bh[4];
      #pragma unroll
      for (int f = 0; f < 4; ++f){
        ah[f] = *(const short8*)&sA[aoff[ks][f]];
        bh[f] = *(const short8*)&sB[boff[ks][f]];
      }
      #pragma unroll
      for (int fm = 0; fm < 4; ++fm)
        #pragma unroll
        for (int fn = 0; fn < 4; ++fn)
          acc[fm][fn] = __builtin_amdgcn_mfma_f32_16x16x32_bf16(ah[fm], bh[fn], acc[fm][fn], 0, 0, 0);
    }
    __syncthreads();
  }

  const int row0 = m0 + wm * 64;
  const int col  = n0 + wn * 64 + (lane & 15);
  float* Cb = Cout + (size_t)b * M * 256;
  #pragma unroll
  for (int fm = 0; fm < 4; ++fm){
    #pragma unroll
    for (int j = 0; j < 4; ++j){
      int row = row0 + fm * 16 + (lane >> 4) * 4 + j;
      float bi = bias[row];
      #pragma unroll
      for (int fn = 0; fn < 4; ++fn)
        Cb[(size_t)row * 256 + col + fn * 16] = acc[fm][fn][j] + bi;
    }
  }

  if (MODE == 0){
    // z8[(b*256+tok)][k] = fp8(z_k*64), PLAIN k (contiguous 4 k's per u32)
    #pragma unroll
    for (int fm = 0; fm < 4; ++fm){
      int rb4 = row0 + fm * 16 + (lane >> 4) * 4;
      float bi0 = bias[rb4], bi1 = bias[rb4+1], bi2 = bias[rb4+2], bi3 = bias[rb4+3];
      #pragma unroll
      for (int fn = 0; fn < 4; ++fn){
        u32 w = f2e4m3((acc[fm][fn][0] + bi0) * 64.0f)
              | (f2e4m3((acc[fm][fn][1] + bi1) * 64.0f) << 8)
              | (f2e4m3((acc[fm][fn][2] + bi2) * 64.0f) << 16)
              | (f2e4m3((acc[fm][fn][3] + bi3) * 64.0f) << 24);
        *(u32*)(Z8 + (size_t)(bbase + col + fn * 16) * 512 + rb4) = w;
      }
    }
  }
}

// ---- GEMM2: MX-scaled fp8 32x32x64 (unity scales = plain fp8 @ 2x rate) ----
// One block/batch (256 blocks, 512 thr, 8 waves 2wm x 4wn, 1/CU, LDS=160KiB).
// SLOT-MAJOR LDS layouts (16B slots) -> conflict-free by construction:
//   B resident: [32 kslot][256 tok][16B] (128KB).  A dbuf: [4 kslot][256 row][16B] x2.
//   16-lane service group reads stride-16B within a slot-plane: 8 bank-groups
//   x 2 lanes = 2-way = free.  No swizzles anywhere.
// Per tile/wave: 8 A-reads + 4 B-reads (b128) + 8 mfma_scale_32x32x64
// (was 64 MFMA): MFMA floor 2483->1100 cyc/tile/CU (4686 TF ubench).
// Fragment: lane l -> row/col = l&31, k = (l>>5)*32 + [0..32) contiguous
// = slots (l>>5)*2, +1.  C/D: col=lane&31, row=(reg&3)+8*(reg>>2)+4*(lane>>5)
// (guide-verified 32x32 mapping).  Scales: E8M0 0x7F = 2^0, cbsz/blgp=0 (fp8).
__global__ __launch_bounds__(512, 1) void k_gemm2(
    const u8* __restrict__ A8,      // emb8 [4096][512B] plain k
    const u8* __restrict__ B8,      // z8 [65536][512B] plain k
    const float* __restrict__ cn26,
    u64* __restrict__ okeys)
{
  __shared__ __align__(16) u8 lds[163840];  // B 0..131071 | A dbuf 131072 + buf*16384

  const int tid  = threadIdx.x;
  const int lane = tid & 63;
  const int wid  = tid >> 6;
  const int wm   = wid >> 2;
  const int wn   = wid & 3;
  const int b    = blockIdx.x;
  const int bbase = b * 256;
  const int lo   = lane & 31;
  const int hi   = lane >> 5;

#define SB    __builtin_amdgcn_sched_barrier(0)
#define BAR   __builtin_amdgcn_s_barrier()
#define VM2   asm volatile("s_waitcnt vmcnt(2)" ::: "memory")
#define VM0   asm volatile("s_waitcnt vmcnt(0)" ::: "memory")

  // ---- B init: slot-major [slot=e>>8][tok=e&255], e = i*512+tid ----
  #pragma unroll
  for (int i = 0; i < 16; ++i){
    int e = i * 512 + tid;          // 0..8191
    gload16((u16*)&lds[e * 16],
            (const u16*)(B8 + (size_t)(bbase + (e & 255)) * 512 + (e >> 8) * 16));
  }

  // ---- A staging: dest linear e*16 (e=tid, tid+512); src slot-major pick ----
  const u8* gsrcA0 = A8 + (size_t)(tid & 255) * 512 + (tid >> 8) * 16;        // slots 0,1
  const u8* gsrcA1 = gsrcA0 + 32;                                             // slots 2,3

#define STG_A(tp) { const size_t _o = (size_t)((tp) >> 3) * 131072 + ((tp) & 7) * 64; \
    const int _d = 131072 + (((tp) & 1) * 16384); \
    gload16((u16*)&lds[_d + tid * 16], (const u16*)(gsrcA0 + _o)); \
    gload16((u16*)&lds[_d + 8192 + tid * 16], (const u16*)(gsrcA1 + _o)); }

  // A-frag read bases: row = wm*128 + fm*32 + lo; slots hi*2, hi*2+1
  int aOff[4];
  #pragma unroll
  for (int fm = 0; fm < 4; ++fm)
    aOff[fm] = 131072 + (hi * 2) * 4096 + (wm * 128 + fm * 32 + lo) * 16;
  // B-frag bases: tok = wn*64 + fnb*32 + lo; slot = kt*4 + hi*2 (kt-dependent)
  int bOff[2];
  #pragma unroll
  for (int fnb = 0; fnb < 2; ++fnb)
    bOff[fnb] = (hi * 2) * 4096 + (wn * 64 + fnb * 32 + lo) * 16;

  f32x16 acc[4][2];
  #pragma unroll
  for (int i = 0; i < 4; ++i)
    #pragma unroll
    for (int j = 0; j < 2; ++j)
      #pragma unroll
      for (int e = 0; e < 16; ++e) acc[i][j][e] = 0.f;

  u64 best[2];
  best[0] = ~0ull; best[1] = ~0ull;

  STG_A(0)

  for (int mt = 0; mt < 16; ++mt){
    #pragma unroll
    for (int kt = 0; kt < 8; ++kt){
      const int tau = mt * 8 + kt;
      if (tau < 127) STG_A(tau + 1)
      if (tau == 127){ VM0; } else { VM2; }
      SB; BAR; SB;                 // tile tau staged & visible

      const int bufo = (tau & 1) * 16384;
      i32x8 av[4], bvv[2];
      #pragma unroll
      for (int fm = 0; fm < 4; ++fm){
        i32x4 l0 = *(const i32x4*)&lds[aOff[fm] + bufo];
        i32x4 h0 = *(const i32x4*)&lds[aOff[fm] + bufo + 4096];
        av[fm] = cat8(l0, h0);
      }
      #pragma unroll
      for (int fnb = 0; fnb < 2; ++fnb){
        i32x4 l0 = *(const i32x4*)&lds[bOff[fnb] + kt * 16384];
        i32x4 h0 = *(const i32x4*)&lds[bOff[fnb] + kt * 16384 + 4096];
        bvv[fnb] = cat8(l0, h0);
      }

      __builtin_amdgcn_s_setprio(1);
      #pragma unroll
      for (int fm = 0; fm < 4; ++fm)
        #pragma unroll
        for (int fnb = 0; fnb < 2; ++fnb)
          acc[fm][fnb] = __builtin_amdgcn_mfma_scale_f32_32x32x64_f8f6f4(
              av[fm], bvv[fnb], acc[fm][fnb],
              0, 0,                       // cbsz=fp8, blgp=fp8
              0, 0x7F7F7F7F,              // scale A opsel, E8M0 2^0
              0, 0x7F7F7F7F);             // scale B opsel, E8M0 2^0
      __builtin_amdgcn_s_setprio(0);
      SB; BAR; SB;                 // all reads of tile tau consumed
    }

    // per-mt epilogue: scores = cn26 - 2*acc, fold packed-u64 argmin.
    // row = (reg&3) + 8*(reg>>2) + 4*hi ; v = mt*256 + wm*128 + fm*32 + row
    #pragma unroll
    for (int fm = 0; fm < 4; ++fm){
      #pragma unroll
      for (int q = 0; q < 4; ++q){
        const int v0 = mt * 256 + wm * 128 + fm * 32 + q * 8 + hi * 4;
        float4 cnr = *(const float4*)(cn26 + v0);
        #pragma unroll
        for (int fnb = 0; fnb < 2; ++fnb){
          #pragma unroll
          for (int j = 0; j < 4; ++j){
            float sc = ((const float*)&cnr)[j] - 2.0f * acc[fm][fnb][q * 4 + j];
            u32 o = __float_as_uint(sc);
            o = (o & 0x80000000u) ? ~o : (o | 0x80000000u);
            best[fnb] = umin64(best[fnb], ((u64)o << 32) | (u32)(v0 + j));
          }
        }
      }
    }
    VM0;   // drain cn loads + early staging: clean vmcnt slate for next mt
    #pragma unroll
    for (int i = 0; i < 4; ++i)
      #pragma unroll
      for (int j = 0; j < 2; ++j)
        #pragma unroll
        for (int e = 0; e < 16; ++e) acc[i][j][e] = 0.f;
  }

  // reduce lane<->lane+32 (same token, different rows), cross-wm via LDS
  best[0] = umin64(best[0], shfl_xor_u64(best[0], 32));
  best[1] = umin64(best[1], shfl_xor_u64(best[1], 32));
  __syncthreads();
  u64* kbuf = (u64*)&lds[131072];
  if (lane < 32){
    kbuf[wm * 256 + wn * 64 + lo]      = best[0];
    kbuf[wm * 256 + wn * 64 + 32 + lo] = best[1];
  }
  __syncthreads();
  if (tid < 256)
    okeys[bbase + tid] = umin64(kbuf[tid], kbuf[256 + tid]);

#undef STG_A
#undef SB
#undef BAR
#undef VM2
#undef VM0
}

// ---- fused tail: GEMM3 (rec) blocks 0..2047 + z_q gather blocks 2048..2303 ----
__global__ __launch_bounds__(256, 4) void k_tail(
    const u16* __restrict__ Ah,      // postw_b [512][512] bf16
    const u16* __restrict__ Bh,      // emb_b [4096][512] bf16
    const u64* __restrict__ gkeys,
    const float* __restrict__ bias,  // post_b
    float* __restrict__ Cout,        // rec
    const float* __restrict__ emb,   // f32 codebook (zq exact)
    float* __restrict__ zq)
{
  constexpr int K = 512;
  __shared__ __align__(16) u16 sA[128 * 64];
  __shared__ __align__(16) u16 sB[128 * 64];

  const int tid = threadIdx.x;

  if (blockIdx.x >= 2048){
    int sidx = (blockIdx.x - 2048) * 256 + tid;
    int b = sidx >> 8, s = sidx & 255;
    int v = (int)(u32)gkeys[sidx];
    const float4* er = (const float4*)(emb + (size_t)v * 512);
    float* o = zq + (size_t)b * 512 * 256 + s;
    #pragma unroll 4
    for (int e4 = 0; e4 < 128; ++e4){
      float4 vv = er[e4];
      o[(size_t)(e4 * 4 + 0) * 256] = vv.x;
      o[(size_t)(e4 * 4 + 1) * 256] = vv.y;
      o[(size_t)(e4 * 4 + 2) * 256] = vv.z;
      o[(size_t)(e4 * 4 + 3) * 256] = vv.w;
    }
    return;
  }

  const int lane = tid & 63;
  const int wid  = tid >> 6;
  const int wm = wid >> 1, wn = wid & 1;

  const int chunk = 2048 >> 3;
  const int pb = blockIdx.x;
  const int bid = (pb & 7) * chunk + (pb >> 3);

  const int mt = bid & 3;
  const int nt = (bid >> 2) & 1;
  const int b  = bid >> 3;
  const int m0 = mt * 128;
  const int n0 = nt * 128;
  const int bbase = b * 256;

  const u16* ga[4];
  const u16* gb[4];
  int ldso[4];
  #pragma unroll
  for (int i = 0; i < 4; ++i){
    int e = i * 256 + tid;
    int r = e >> 3;
    int sl = (e & 7) ^ (r & 7);
    ldso[i] = e * 8;
    ga[i] = Ah + (size_t)(m0 + r) * K + sl * 8;
    size_t brow = (size_t)(u32)gkeys[bbase + n0 + r];
    gb[i] = Bh + brow * K + sl * 8;
  }

  const f32x4 zero4 = {0.f, 0.f, 0.f, 0.f};
  f32x4 acc[4][4];
  #pragma unroll
  for (int i = 0; i < 4; ++i)
    #pragma unroll
    for (int j = 0; j < 4; ++j) acc[i][j] = zero4;

  int aoff[2][4], boff[2][4];
  #pragma unroll
  for (int ks = 0; ks < 2; ++ks)
    #pragma unroll
    for (int f = 0; f < 4; ++f){
      int rA = wm * 64 + f * 16 + (lane & 15);
      aoff[ks][f] = rA * 64 + (((ks * 4 + (lane >> 4)) ^ (rA & 7)) * 8);
      int rB = wn * 64 + f * 16 + (lane & 15);
      boff[ks][f] = rB * 64 + (((ks * 4 + (lane >> 4)) ^ (rB & 7)) * 8);
    }

  for (int kt = 0; kt < 8; ++kt){
    const int k0 = kt * 64;
    #pragma unroll
    for (int i = 0; i < 4; ++i){
      gload16(&sA[ldso[i]], ga[i] + k0);
      gload16(&sB[ldso[i]], gb[i] + k0);
    }
    __syncthreads();
    #pragma unroll
    for (int ks = 0; ks < 2; ++ks){
      short8 ah[4], bh[4];
      #pragma unroll
      for (int f = 0; f < 4; ++f){
        ah[f] = *(const short8*)&sA[aoff[ks][f]];
        bh[f] = *(const short8*)&sB[boff[ks][f]];
      }
      #pragma unroll
      for (int fm = 0; fm < 4; ++fm)
        #pragma unroll
        for (int fn = 0; fn < 4; ++fn)
          acc[fm][fn] = __builtin_amdgcn_mfma_f32_16x16x32_bf16(ah[fm], bh[fn], acc[fm][fn], 0, 0, 0);
    }
    __syncthreads();
  }

  const int row0 = m0 + wm * 64;
  const int col  = n0 + wn * 64 + (lane & 15);
  float* Cb = Cout + (size_t)b * K * 256;
  #pragma unroll
  for (int fm = 0; fm < 4; ++fm){
    #pragma unroll
    for (int j = 0; j < 4; ++j){
      int row = row0 + fm * 16 + (lane >> 4) * 4 + j;
      float bi = bias[row];
      #pragma unroll
      for (int fn = 0; fn < 4; ++fn)
        Cb[(size_t)row * 256 + col + fn * 16] = acc[fm][fn][j] + bi;
    }
  }
}

extern "C" void kernel_launch(void* const* d_in, const int* in_sizes, int n_in,
                              void* d_out, int out_size, void* d_ws, size_t ws_size,
                              hipStream_t stream){
  const float* x      = (const float*)d_in[0];
  const float* pre_w  = (const float*)d_in[1];
  const float* pre_b  = (const float*)d_in[2];
  const float* emb    = (const float*)d_in[3];
  const float* post_w = (const float*)d_in[4];
  const float* post_b = (const float*)d_in[5];

  float* z_out   = (float*)d_out;              // [256][512][256]
  float* zq_out  = z_out + 33554432;           // [256][512][256]
  float* rec_out = z_out + 67108864;           // [256][512][256]

  char* w = (char*)d_ws;
  u16* prew_b  = (u16*)(w);                    // 512KB
  u16* postw_b = (u16*)(w + 524288);           // 512KB
  u16* emb_b   = (u16*)(w + 1048576);          // 4MB (bf16, GEMM3)
  u8*  emb8    = (u8*)(w + 5242880);           // 2MB (fp8 plain k)
  float* cn26  = (float*)(w + 7340032);        // 16KB
  u64* keys    = (u64*)(w + 7356416);          // 512KB
  u16* xb      = (u16*)(w + 7880704);          // 64MB [65536][512] bf16 (x^T)
  u8*  z8      = (u8*)(w + 74989568);          // 32MB [65536][512B] fp8 plain k (z^T)

  // 1. fused prep
  k_prep<<<21504, 256, 0, stream>>>(x, pre_w, post_w, emb,
                                    xb, prew_b, postw_b, emb_b, emb8, cn26);

  // 2. GEMM1: z = pre_w * x + pre_b ; fused z8 (fp8 plain-k transposed) write
  k_gemm<0><<<256 * 2 * 4, 256, 0, stream>>>(prew_b, xb,
      nullptr, pre_b, z_out, z8, 512, 2);

  // 3. GEMM2: MX-fp8 32x32x64 scores + fused argmin -> keys
  k_gemm2<<<256, 512, 0, stream>>>(emb8, z8, cn26, keys);

  // 4. fused tail: GEMM3 (rec) + z_q gather
  k_tail<<<2048 + 256, 256, 0, stream>>>(postw_b, emb_b, keys, post_b,
                                         rec_out, emb, zq_out);
}